// Round 2
// baseline (490.943 us; speedup 1.0000x reference)
//
#include <hip/hip_runtime.h>
#include <cstdint>
#include <cstddef>

// Problem constants: B=128, L=64, F=3072, D=1024, CV=512, CN=1024, MAX_K=8
typedef unsigned short u16;
typedef __attribute__((ext_vector_type(8))) short short8;   // 8 x bf16 (4 VGPRs)
typedef __attribute__((ext_vector_type(4))) float f32x4;    // MFMA accumulator

static __device__ __forceinline__ float bf2f(u16 h) {
  union { unsigned u; float f; } a; a.u = ((unsigned)h) << 16; return a.f;
}
static __device__ __forceinline__ u16 f2bf(float x) {
  union { float f; unsigned u; } a; a.f = x;
  return (u16)((a.u + 0x7fffu + ((a.u >> 16) & 1u)) >> 16);  // RNE
}

// async global->LDS, 16B per lane. LDS dest is wave-uniform base + lane*16.
#define GLDS16(gp, lp)                                                          \
  __builtin_amdgcn_global_load_lds(                                             \
      (const __attribute__((address_space(1))) void*)(gp),                      \
      (__attribute__((address_space(3))) void*)(lp), 16, 0, 0)

template<int N> static __device__ __forceinline__ void vmwait() {
  if constexpr (N == 0)      asm volatile("s_waitcnt vmcnt(0)" ::: "memory");
  else if constexpr (N == 3) asm volatile("s_waitcnt vmcnt(3)" ::: "memory");
  else if constexpr (N == 4) asm volatile("s_waitcnt vmcnt(4)" ::: "memory");
  else if constexpr (N == 6) asm volatile("s_waitcnt vmcnt(6)" ::: "memory");
  else if constexpr (N == 8) asm volatile("s_waitcnt vmcnt(8)" ::: "memory");
  // N >= 63: no wait
}

// ------------------------------------------------------------- merged prep
// Grid-strided (G11): [0,2048) cast ×12/thread; [2048,2816) transpose ×12 tiles;
// [2816,3328) verb-weight prep; [3328,4352) noun-weight prep; [4352,5376) e1pad pad-zero.
__global__ void prep_all(const float* __restrict__ inputs, u16* __restrict__ Xbf,
                         const float* __restrict__ W0, const float* __restrict__ W1,
                         const float* __restrict__ W2, u16* __restrict__ Wt,
                         const float* __restrict__ Kv, const float* __restrict__ bv,
                         const float* __restrict__ g_v, const float* __restrict__ beta_v,
                         const float* __restrict__ mean_v, const float* __restrict__ var_v,
                         u16* __restrict__ KVt, float* __restrict__ biasv,
                         const float* __restrict__ Kn, const float* __restrict__ bnb,
                         const float* __restrict__ g_n, const float* __restrict__ beta_n,
                         const float* __restrict__ mean_n, const float* __restrict__ var_n,
                         u16* __restrict__ KNt, float* __restrict__ biasn,
                         u16* __restrict__ e1pad) {
  __shared__ float tile[32][33];
  const int id = blockIdx.x;
  const int tid = threadIdx.x;
  if (id < 2048) {                        // cast: 12 float4 per thread, grid-stride
    int i = id * 256 + tid;               // total 2048*256*12 = 6291456 exactly
#pragma unroll
    for (int it = 0; it < 12; it++) {
      float4 v = ((const float4*)inputs)[i];
      ushort4 o;
      o.x = f2bf(v.x); o.y = f2bf(v.y); o.z = f2bf(v.z); o.w = f2bf(v.w);
      ((ushort4*)Xbf)[i] = o;
      i += 2048 * 256;
    }
  } else if (id < 2816) {                 // transpose W: 768 blocks x 12 tiles = 9216
    const int tx = tid & 31, ty = tid >> 5;
    for (int it = 0; it < 12; it++) {
      const int tl = (id - 2048) + 768 * it;
      const int kb = (tl % 96) * 32;
      const int jb = (tl / 96) * 32;
      const int w = jb >> 10;
      const float* W = (w == 0) ? W0 : ((w == 1) ? W1 : W2);
      const int nb = jb & 1023;
#pragma unroll
      for (int i = 0; i < 4; i++)
        tile[ty + 8 * i][tx] = W[(size_t)(kb + ty + 8 * i) * 1024 + nb + tx];
      __syncthreads();
#pragma unroll
      for (int i = 0; i < 4; i++)
        Wt[(size_t)(jb + ty + 8 * i) * 3072 + kb + tx] = f2bf(tile[tx][ty + 8 * i]);
      __syncthreads();
    }
  } else if (id < 3328) {                 // prep_kv
    const int c = id - 2816;
    const float scale = g_v[c] * rsqrtf(var_v[c] + 1e-5f);
    for (int t = 0; t < 3; t++)
      for (int d = tid; d < 1024; d += 256)
        KVt[(size_t)c * 3072 + t * 1024 + d] = f2bf(Kv[(size_t)c * 3072 + d * 3 + t] * scale);
    if (tid == 0) biasv[c] = (bv[c] - mean_v[c]) * scale + beta_v[c];
  } else if (id < 4352) {                 // prep_kn
    const int c = id - 3328;
    const float scale = g_n[c] * rsqrtf(var_n[c] + 1e-5f);
    for (int d = tid; d < 1024; d += 256)
      KNt[(size_t)c * 1024 + d] = f2bf(Kn[(size_t)c * 1024 + d] * scale);
    if (tid == 0) biasn[c] = (bnb[c] - mean_n[c]) * scale + beta_n[c];
  } else {                                // zero pad rows 0,65 of e1pad (B,66,D)
    const int i = (id - 4352) * 256 + tid;    // 0..262143
    const int b = i >> 11;
    const int j = i & 2047;
    const int r = (j < 1024) ? 0 : 65;
    const int d = j & 1023;
    e1pad[(size_t)(b * 66 + r) * 1024 + d] = 0;
  }
}

// =====================================================================
// Pipelined GEMM core: BM=128, BN=FJ*64, BK=32, 512 threads = 8 waves
// (2M x 4N), per-wave 64 x FJ*16 via acc[4][FJ] mfma_f32_16x16x32_bf16.
//
// LDS ring-4: slot = A 128x32 (8KB) + B FJ*64x32 (FJ*4KB). Tile t computed
// from slot t&3 while t+1..t+3 stream in. G = 1+FJ/2 GLDS16/thread/tile.
// ONE barrier per K-tile: end-of-tile {vmcnt(2G) -> s_barrier} both
// guarantees tile t+1 fully in LDS (FIFO vmcnt retire) and orders all
// waves' slot reads before the next overwrite. Waves free-run within a
// tile -> MFMA of one wave overlaps ds_reads/staging of another.
//
// Row swizzle: 4 chunks of 16B per 64B row; chunk c of row r stored at
// position (c+r)&3. Staging keeps LDS dest linear and pre-swizzles the
// per-lane GLOBAL source chunk (rule #21); reads add ((quad+l15)&3)*8.
// =====================================================================
#define PIPE_DECLS(FJv)                                                         \
  constexpr int FJ = (FJv);                                                     \
  constexpr int SLOTU = 4096 + FJ * 2048;                                       \
  constexpr int NBG = FJ / 2;                                                   \
  constexpr int G = 1 + NBG;                                                    \
  const int tid = threadIdx.x;                                                  \
  const int lane = tid & 63;                                                    \
  const int warp = tid >> 6;                                                    \
  const int wm = warp & 1, wn = warp >> 1;                                      \
  const int l15 = lane & 15, quad = lane >> 4;                                  \
  u16* stA = lds + tid * 8;                                                     \
  u16* stB = lds + 4096 + tid * 8;                                              \
  const u16* rdA = lds + (wm * 64 + l15) * 32;                                  \
  const u16* rdB = lds + 4096 + (wn * (FJ * 16) + l15) * 32;                    \
  const int pA = ((quad + l15) & 3) * 8;

#define STAGE_(NSL, KO)                                                         \
  {                                                                             \
    const size_t ko_ = (KO);                                                    \
    GLDS16(gA + ko_, stA + (NSL) * SLOTU);                                      \
    _Pragma("unroll")                                                           \
    for (int g = 0; g < NBG; g++)                                               \
      GLDS16(gB + (size_t)g * gBgrp + ko_, stB + (NSL) * SLOTU + g * 4096);     \
  }

#define BODY_(SL, NSL, T, DOSTAGE, VM)                                          \
  {                                                                             \
    const u16* ra = rdA + (SL) * SLOTU + pA;                                    \
    const u16* rb = rdB + (SL) * SLOTU + pA;                                    \
    short8 fa[4];                                                               \
    short8 fb[FJ];                                                              \
    _Pragma("unroll")                                                           \
    for (int i = 0; i < 4; i++) fa[i] = *(const short8*)(ra + i * 512);         \
    _Pragma("unroll")                                                           \
    for (int j = 0; j < FJ; j++) fb[j] = *(const short8*)(rb + j * 512);        \
    if (DOSTAGE) STAGE_(NSL, (size_t)((T) + 3) * 32);                           \
    __builtin_amdgcn_sched_barrier(0);                                          \
    __builtin_amdgcn_s_setprio(1);                                              \
    _Pragma("unroll")                                                           \
    for (int i = 0; i < 4; i++)                                                 \
      _Pragma("unroll")                                                         \
      for (int j = 0; j < FJ; j++)                                              \
        acc[i][j] = __builtin_amdgcn_mfma_f32_16x16x32_bf16(fa[i], fb[j],       \
                                                            acc[i][j], 0, 0, 0);\
    __builtin_amdgcn_s_setprio(0);                                              \
    vmwait<VM>();                                                               \
    __builtin_amdgcn_s_barrier();                                               \
    __builtin_amdgcn_sched_barrier(0);                                          \
  }

// gA: per-thread A src (row tid>>2 of the M-tile, pre-swizzled chunk), +32 u16/tile.
// gB: per-thread B src for group 0 (row n0 + tid>>2); gBgrp = 128*ldB.
template<int FJv, int NT>
static __device__ __forceinline__ void gemm_pipe(
    const u16* __restrict__ gA, const u16* __restrict__ gB, const size_t gBgrp,
    u16* lds, f32x4 (*acc)[FJv]) {
  PIPE_DECLS(FJv)

  // prologue: stage tiles 0,1,2 into slots 0,1,2
  STAGE_(0, 0);
  STAGE_(1, 32);
  STAGE_(2, 64);
  vmwait<2 * G>();                       // tile 0 landed; 1,2 in flight
  __builtin_amdgcn_s_barrier();
  __builtin_amdgcn_sched_barrier(0);

  int t = 0;
#pragma unroll 1
  for (; t < NT - 4; t += 4) {
    BODY_(0, 3, t,     true, 2 * G);
    BODY_(1, 0, t + 1, true, 2 * G);
    BODY_(2, 1, t + 2, true, 2 * G);
    BODY_(3, 2, t + 3, true, 2 * G);
  }
  // t == NT-4: last group, drain with exact counts (never stalls early)
  BODY_(0, 3, t,     true,  2 * G);      // stages tile NT-1
  BODY_(1, 0, t + 1, false, G);
  BODY_(2, 1, t + 2, false, 0);
  BODY_(3, 2, t + 3, false, 63);
}

// epilogue: sigmoid + per-column top-8 + mean of top-k (per-wave batch)
static __device__ __forceinline__ void topk_epilogue(
    f32x4 (*acc)[4], const float* __restrict__ bias,
    const int* __restrict__ lens, float* __restrict__ out,
    const int NC, const int m0, const int n0) {
  const int tid = threadIdx.x;
  const int lane = tid & 63;
  const int warp = tid >> 6;
  const int wm = warp & 1, wn = warp >> 1;
  const int l15 = lane & 15, quad = lane >> 4;
  const int b = (m0 >> 6) + wm;            // this wave's batch
  const int len = lens[b];
  const int kk8 = (len + 7) >> 3;          // k = ceil(len/8), 1..8
#pragma unroll
  for (int j = 0; j < 4; j++) {
    const int c = n0 + wn * 64 + j * 16 + l15;
    const float bias_c = bias[c];
    float t[8];
#pragma unroll
    for (int q8 = 0; q8 < 8; q8++) t[q8] = -1e30f;
#pragma unroll
    for (int i = 0; i < 4; i++) {
#pragma unroll
      for (int r = 0; r < 4; r++) {
        const int l = i * 16 + quad * 4 + r;
        const float v = acc[i][j][r] + bias_c;
        const float sg = 1.0f / (1.0f + __expf(-v));
        float x = (l < len) ? sg : -1e30f;
#pragma unroll
        for (int q8 = 0; q8 < 8; q8++) {   // branchless sorted insert (desc)
          const float hi = fmaxf(t[q8], x);
          x = fminf(t[q8], x);
          t[q8] = hi;
        }
      }
    }
    // merge top-8 lists across the 4 quads (lanes ^16, ^32).
    // SNAPSHOT the partner's entire list BEFORE inserting anything.
#pragma unroll
    for (int mask = 16; mask <= 32; mask <<= 1) {
      float xs[8];
#pragma unroll
      for (int q8 = 0; q8 < 8; q8++) xs[q8] = __shfl_xor(t[q8], mask);
#pragma unroll
      for (int q8 = 0; q8 < 8; q8++) {
        float x = xs[q8];
#pragma unroll
        for (int p8 = 0; p8 < 8; p8++) {
          const float hi = fmaxf(t[p8], x);
          x = fminf(t[p8], x);
          t[p8] = hi;
        }
      }
    }
    if (quad == 0) {
      float s = 0.f;
#pragma unroll
      for (int q8 = 0; q8 < 8; q8++) s += (q8 < kk8) ? t[q8] : 0.f;
      out[(size_t)b * NC + c] = s / (float)kk8;
    }
  }
}

// ------------------------------------------------------------------ embed GEMM
// grid (8, 64): bx = N-tile (384 cols), by = M-tile (128 rows). 512 blocks
// = 2 exact rounds of 256 CUs. id%8 == bx -> each XCD keeps one 2.36MB
// B-panel L2-resident (natural XCD affinity, no swizzle needed).
__global__ __launch_bounds__(512, 2) void gemm_embed(
    const u16* __restrict__ A, const u16* __restrict__ Bmat,
    const float* __restrict__ bias0, const float* __restrict__ bias1,
    const float* __restrict__ bias2,
    float* __restrict__ oute1, float* __restrict__ oute2,
    u16* __restrict__ e0bf, u16* __restrict__ e1pad, u16* __restrict__ e2bf) {
  __shared__ __align__(16) u16 lds[4 * (4096 + 6 * 2048)];   // 128 KiB
  const int tid = threadIdx.x;
  const int m0 = blockIdx.y * 128;
  const int n0 = blockIdx.x * 384;
  const int u = tid >> 2;                           // staged row (0..127)
  const int cs = (((tid & 3) - u) & 3) * 8;         // pre-swizzled source chunk

  f32x4 acc[4][6];
#pragma unroll
  for (int i = 0; i < 4; i++)
#pragma unroll
    for (int j = 0; j < 6; j++) acc[i][j] = (f32x4){0.f, 0.f, 0.f, 0.f};

  gemm_pipe<6, 96>(A + (size_t)(m0 + u) * 3072 + cs,
                   Bmat + (size_t)(n0 + u) * 3072 + cs, (size_t)128 * 3072,
                   lds, acc);

  const int lane = tid & 63;
  const int warp = tid >> 6;
  const int wm = warp & 1, wn = warp >> 1;
  const int l15 = lane & 15, quad = lane >> 4;
#pragma unroll
  for (int j = 0; j < 6; j++) {
    const int cb = n0 + wn * 96 + j * 16;           // frag never straddles 1024
    const int w = cb >> 10;
    const int n = (cb & 1023) + l15;
    const float bias = ((w == 0) ? bias0 : (w == 1) ? bias1 : bias2)[n];
#pragma unroll
    for (int i = 0; i < 4; i++) {
      const int mr = m0 + wm * 64 + i * 16 + quad * 4;
#pragma unroll
      for (int r = 0; r < 4; r++) {
        const int m = mr + r;
        const float v = acc[i][j][r] + bias;
        if (w == 0) {
          e0bf[(size_t)m * 1024 + n] = f2bf(v);
        } else if (w == 1) {
          oute1[(size_t)m * 1024 + n] = v;
          e1pad[(size_t)((m >> 6) * 66 + (m & 63) + 1) * 1024 + n] = f2bf(v);
        } else {
          oute2[(size_t)m * 1024 + n] = v;
          e2bf[(size_t)m * 1024 + n] = f2bf(v);
        }
      }
    }
  }
}

// fused tail: [0,128) verb GEMM+topk (NC=512, K=3072 im2col);
// [128,384) noun GEMM+topk (NC=1024, K=1024); [384,512) attention pooling.
// 512 blocks = 2 exact rounds; verb (longest) dispatched first.
__global__ __launch_bounds__(512, 2) void fused_tail(
    const u16* __restrict__ e1pad, const u16* __restrict__ KVt,
    const float* __restrict__ biasv,
    const u16* __restrict__ e2bf, const u16* __restrict__ KNt,
    const float* __restrict__ biasn,
    const u16* __restrict__ e0bf, const float* __restrict__ w_attn,
    const float* __restrict__ b_attn, const int* __restrict__ lens,
    float* __restrict__ out_sent, float* __restrict__ out_ilv,
    float* __restrict__ out_iln) {
  __shared__ __align__(16) u16 smem[4 * (4096 + 4 * 2048)];  // 96 KiB
  const int id = blockIdx.x;
  const int tid = threadIdx.x;
  if (id < 384) {
    const int u = tid >> 2;
    const int cs = (((tid & 3) - u) & 3) * 8;
    f32x4 acc[4][4];
#pragma unroll
    for (int i = 0; i < 4; i++)
#pragma unroll
      for (int j = 0; j < 4; j++) acc[i][j] = (f32x4){0.f, 0.f, 0.f, 0.f};
    if (id < 128) {
      // verb: A row m (batch bb = m>>6, pos l = m&63) is the contiguous 3072
      // u16 at e1pad[(bb*66 + l)*1024] (3-tap im2col is flat in the padded
      // layout). LDS row u -> e1pad row: u<64 -> batch 2by row u; else
      // batch 2by+1 row u-64 => offset (u+2)*1024.
      const int by = id >> 1, bx = id & 1;
      const int n0 = bx * 256;
      const int rowoff = (u < 64) ? u : (u + 2);
      gemm_pipe<4, 96>(e1pad + ((size_t)(by * 2) * 66 + rowoff) * 1024 + cs,
                       KVt + (size_t)(n0 + u) * 3072 + cs, (size_t)128 * 3072,
                       smem, acc);
      topk_epilogue(acc, biasv, lens, out_ilv, 512, by * 128, n0);
    } else {
      const int id2 = id - 128;
      const int by = id2 >> 2, bx = id2 & 3;
      const int m0 = by * 128, n0 = bx * 256;
      gemm_pipe<4, 32>(e2bf + (size_t)(m0 + u) * 1024 + cs,
                       KNt + (size_t)(n0 + u) * 1024 + cs, (size_t)128 * 1024,
                       smem, acc);
      topk_epilogue(acc, biasn, lens, out_iln, 1024, m0, n0);
    }
  } else {
    // ---- attention pooling, one block per batch (gated sections use 256
    // threads; barriers reached by all 512).
    const int b = id - 384;
    const int lane = tid & 63;
    const int warp = tid >> 6;
    float* sc = (float*)smem;        // 64 floats
    float* at = sc + 64;             // 64 floats
    const int len = lens[b];
    if (warp < 4) {
      for (int t = 0; t < 16; t++) {
        const int l = warp * 16 + t;
        const u16* row = e0bf + (size_t)(b * 64 + l) * 1024;
        float s = 0.f;
#pragma unroll
        for (int uu = 0; uu < 16; uu++) {
          const int d = lane + uu * 64;
          s += bf2f(row[d]) * w_attn[d];
        }
#pragma unroll
        for (int off = 32; off > 0; off >>= 1) s += __shfl_down(s, off);
        if (lane == 0) sc[l] = s + b_attn[0];
      }
    }
    __syncthreads();
    if (warp == 0) {
      float v = (lane < len) ? sc[lane] : -1e30f;
      float m = v;
#pragma unroll
      for (int off = 32; off > 0; off >>= 1) m = fmaxf(m, __shfl_xor(m, off));
      float p = (lane < len) ? __expf(v - m) : 0.f;
      float ssum = p;
#pragma unroll
      for (int off = 32; off > 0; off >>= 1) ssum += __shfl_xor(ssum, off);
      at[lane] = p / ssum;
    }
    __syncthreads();
    if (tid < 256) {
      const int d0 = tid * 4;
      float a0 = 0.f, a1 = 0.f, a2 = 0.f, a3 = 0.f;
      for (int l = 0; l < 64; l++) {
        const float wgt = at[l];
        const ushort4 u4 = *(const ushort4*)(e0bf + (size_t)(b * 64 + l) * 1024 + d0);
        a0 += wgt * bf2f(u4.x);
        a1 += wgt * bf2f(u4.y);
        a2 += wgt * bf2f(u4.z);
        a3 += wgt * bf2f(u4.w);
      }
      float4 o; o.x = a0; o.y = a1; o.z = a2; o.w = a3;
      *(float4*)(out_sent + (size_t)b * 1024 + d0) = o;
    }
  }
}

// --------------------------------------------------------------------- launch
extern "C" void kernel_launch(void* const* d_in, const int* in_sizes, int n_in,
                              void* d_out, int out_size, void* d_ws, size_t ws_size,
                              hipStream_t stream) {
  const float* inputs = (const float*)d_in[0];
  const int*   lens   = (const int*)d_in[1];
  const float* W0 = (const float*)d_in[2];
  const float* b0 = (const float*)d_in[3];
  const float* W1 = (const float*)d_in[4];
  const float* b1 = (const float*)d_in[5];
  const float* W2 = (const float*)d_in[6];
  const float* b2 = (const float*)d_in[7];
  const float* w_attn = (const float*)d_in[8];
  const float* b_attn = (const float*)d_in[9];
  const float* Kv   = (const float*)d_in[10];
  const float* bv   = (const float*)d_in[11];
  const float* g_v  = (const float*)d_in[12];
  const float* beta_v = (const float*)d_in[13];
  const float* mean_v = (const float*)d_in[14];
  const float* var_v  = (const float*)d_in[15];
  const float* Kn   = (const float*)d_in[16];
  const float* bn_b = (const float*)d_in[17];
  const float* g_n  = (const float*)d_in[18];
  const float* beta_n = (const float*)d_in[19];
  const float* mean_n = (const float*)d_in[20];
  const float* var_n  = (const float*)d_in[21];

  float* out = (float*)d_out;
  float* out_sent = out;                               // (128,1024)
  float* out_e1   = out + 131072;                      // (128,64,1024)
  float* out_e2   = out + 131072 + 8388608;            // (128,64,1024)
  float* out_ilv  = out + 131072 + 2 * 8388608;        // (128,512)
  float* out_iln  = out_ilv + 65536;                   // (128,1024)

  // workspace carve
  char* p = (char*)d_ws;
  u16* Xbf  = (u16*)p; p += (size_t)8192 * 3072 * 2;   // inputs bf16
  u16* Wt   = (u16*)p; p += (size_t)3072 * 3072 * 2;   // [W0|W1|W2]^T, N-major
  u16* KVt  = (u16*)p; p += (size_t)512 * 3072 * 2;    // verb weights, BN-folded
  u16* KNt  = (u16*)p; p += (size_t)1024 * 1024 * 2;   // noun weights, BN-folded
  float* biasv = (float*)p; p += 512 * 4;
  float* biasn = (float*)p; p += 1024 * 4;
  u16* e0bf  = (u16*)p; p += (size_t)8192 * 1024 * 2;
  u16* e1pad = (u16*)p; p += (size_t)128 * 66 * 1024 * 2;  // (B,66,D) zero-padded
  u16* e2bf  = (u16*)p; p += (size_t)8192 * 1024 * 2;

  prep_all<<<5376, 256, 0, stream>>>(inputs, Xbf, W0, W1, W2, Wt,
                                     Kv, bv, g_v, beta_v, mean_v, var_v, KVt, biasv,
                                     Kn, bn_b, g_n, beta_n, mean_n, var_n, KNt, biasn,
                                     e1pad);
  gemm_embed<<<dim3(8, 64), 512, 0, stream>>>(Xbf, Wt, b0, b1, b2, out_e1, out_e2,
                                              e0bf, e1pad, e2bf);
  fused_tail<<<512, 512, 0, stream>>>(e1pad, KVt, biasv, e2bf, KNt, biasn,
                                      e0bf, w_attn, b_attn, lens,
                                      out_sent, out_ilv, out_iln);
}